// Round 1
// baseline (367.593 us; speedup 1.0000x reference)
//
#include <hip/hip_runtime.h>

// MaskedPooling: out[b,d] = sum_t x[b,t,d]*keep[b,t] / sum_t keep[b,t]
// x: [B=32, T=4096, D=512] fp32; mask: [B,T] int (nonzero = excluded)

#define BB 32
#define TT 4096
#define DD 512
#define SPLITS 32
#define ROWS_PER_BLOCK (TT / SPLITS)   // 128 rows per block

__global__ __launch_bounds__(256) void masked_pool_partial(
    const float* __restrict__ x, const int* __restrict__ mask,
    float* __restrict__ out)
{
    __shared__ float s_keep[ROWS_PER_BLOCK];
    const int b   = blockIdx.x;
    const int s   = blockIdx.y;
    const int tid = threadIdx.x;
    const int t0  = s * ROWS_PER_BLOCK;

    // Stage keep factors (1.0 where mask==0, else 0.0) into LDS once.
    if (tid < ROWS_PER_BLOCK) {
        s_keep[tid] = (mask[b * TT + t0 + tid] == 0) ? 1.0f : 0.0f;
    }
    __syncthreads();

    const int tx = tid & 127;   // float4 column: covers D=512 floats
    const int ty = tid >> 7;    // 0..1 row-group

    const float4* xrow = (const float4*)(x + (size_t)b * TT * DD)
                         + (size_t)t0 * (DD / 4);

    float4 acc = make_float4(0.f, 0.f, 0.f, 0.f);
    #pragma unroll 8
    for (int r = ty; r < ROWS_PER_BLOCK; r += 2) {
        float  k = s_keep[r];                         // LDS broadcast, no conflict
        float4 v = xrow[(size_t)r * (DD / 4) + tx];   // coalesced 16B/lane
        acc.x += k * v.x;
        acc.y += k * v.y;
        acc.z += k * v.z;
        acc.w += k * v.w;
    }

    float* o = out + (size_t)b * DD + tx * 4;
    atomicAdd(o + 0, acc.x);
    atomicAdd(o + 1, acc.y);
    atomicAdd(o + 2, acc.z);
    atomicAdd(o + 3, acc.w);
}

__global__ __launch_bounds__(256) void masked_pool_scale(
    const int* __restrict__ mask, float* __restrict__ out)
{
    const int b   = blockIdx.x;
    const int tid = threadIdx.x;

    // denom[b] = count of kept positions
    int cnt = 0;
    #pragma unroll
    for (int t = tid; t < TT; t += 256) cnt += (mask[b * TT + t] == 0) ? 1 : 0;

    // wave (64-lane) shuffle reduce, then cross-wave via LDS
    #pragma unroll
    for (int off = 32; off > 0; off >>= 1) cnt += __shfl_down(cnt, off, 64);

    __shared__ int s_cnt[4];
    if ((tid & 63) == 0) s_cnt[tid >> 6] = cnt;
    __syncthreads();

    const int denom = s_cnt[0] + s_cnt[1] + s_cnt[2] + s_cnt[3];
    const float inv = 1.0f / (float)denom;

    for (int d = tid; d < DD; d += 256) out[(size_t)b * DD + d] *= inv;
}

extern "C" void kernel_launch(void* const* d_in, const int* in_sizes, int n_in,
                              void* d_out, int out_size, void* d_ws, size_t ws_size,
                              hipStream_t stream) {
    const float* x    = (const float*)d_in[0];
    const int*   mask = (const int*)d_in[1];
    float*       out  = (float*)d_out;

    // d_out is poisoned 0xAA before every launch; we accumulate into it.
    hipMemsetAsync(out, 0, (size_t)out_size * sizeof(float), stream);

    dim3 grid(BB, SPLITS);
    masked_pool_partial<<<grid, 256, 0, stream>>>(x, mask, out);
    masked_pool_scale<<<BB, 256, 0, stream>>>(mask, out);
}